// Round 5
// baseline (8744.798 us; speedup 1.0000x reference)
//
#include <hip/hip_runtime.h>

// RNN: xp = x@Wx^T + b (GEMM, bf16 MFMA), then 512-step scan
// h_t = tanh(xp_t + h_{t-1}@Wh^T).
// Scan: 4 groups x 16 WGs x 4 waves. Each WAVE is fully independent:
// owns 16 j x full K=1024 (Wh tile AGPR-pinned, 32 frags), 16 batches.
// No LDS, no barriers, no flags. h packs carry 2-bit epoch in bf16 LSBs;
// consumers poll the data itself via relaxed agent-scope (MALL) loads.

typedef unsigned short u16;
typedef unsigned long long u64;
typedef __attribute__((ext_vector_type(4))) float f32x4;
typedef __attribute__((ext_vector_type(8))) short bf16x8;

__device__ __forceinline__ u16 f2bf(float f) {
  unsigned u = __builtin_bit_cast(unsigned, f);
  unsigned r = (u + 0x7fffu + ((u >> 16) & 1u)) >> 16;  // RTN-even
  return (u16)r;
}

// bf16 with bit0 forced to `bit` (<=1 ULP error: trunc or trunc+1)
__device__ __forceinline__ u16 f2bf_par(float f, unsigned bit) {
  unsigned rt = __builtin_bit_cast(unsigned, f) >> 16;  // truncate
  return (u16)(((rt & 1u) == bit) ? rt : rt + 1u);
}

__device__ __forceinline__ void async_cp16(u16* lds, const u16* g) {
  __builtin_amdgcn_global_load_lds(
      (const __attribute__((address_space(1))) unsigned int*)g,
      (__attribute__((address_space(3))) unsigned int*)lds, 16, 0, 0);
}

// ---------------- conversion kernels ----------------

__global__ __launch_bounds__(256) void conv_x_kernel(const float* __restrict__ in,
                                                     u16* __restrict__ outb) {
  const size_t i = (size_t)blockIdx.x * 256 + threadIdx.x;  // 8-elem chunk id
  const float4* p = (const float4*)(in + (i << 3));
  float4 a = p[0], b = p[1];
  bf16x8 v;
  v[0] = (short)f2bf(a.x); v[1] = (short)f2bf(a.y);
  v[2] = (short)f2bf(a.z); v[3] = (short)f2bf(a.w);
  v[4] = (short)f2bf(b.x); v[5] = (short)f2bf(b.y);
  v[6] = (short)f2bf(b.z); v[7] = (short)f2bf(b.w);
  *(bf16x8*)(outb + (i << 3)) = v;
}

__global__ __launch_bounds__(256) void conv_w_kernel(const float* __restrict__ W,
                                                     u16* __restrict__ Wx,
                                                     u16* __restrict__ Wh) {
  const int i = blockIdx.x * 256 + threadIdx.x;  // 8-elem chunk id, 2048/row
  const int j = i >> 8;          // row 0..1023
  const int c = (i & 255) << 3;  // col 0..2040
  const float4* p = (const float4*)(W + (size_t)j * 2048 + c);
  float4 a = p[0], b = p[1];
  bf16x8 v;
  v[0] = (short)f2bf(a.x); v[1] = (short)f2bf(a.y);
  v[2] = (short)f2bf(a.z); v[3] = (short)f2bf(a.w);
  v[4] = (short)f2bf(b.x); v[5] = (short)f2bf(b.y);
  v[6] = (short)f2bf(b.z); v[7] = (short)f2bf(b.w);
  u16* dst = (c < 1024) ? (Wx + (size_t)j * 1024 + c)
                        : (Wh + (size_t)j * 1024 + (c - 1024));
  *(bf16x8*)dst = v;
}

// ---------------- Phase 1: xp GEMM (m97 structure) ----------------

__global__ __launch_bounds__(256, 2) void gemm_xp(const u16* __restrict__ A,
                                                  const u16* __restrict__ B,
                                                  const float* __restrict__ bias,
                                                  float* __restrict__ C) {
  const int bid = blockIdx.x;                    // 2048 blocks
  const int swz = (bid & 7) * 256 + (bid >> 3);  // XCD-aware swizzle (nwg%8==0)
  const int m0 = (swz >> 3) << 7;
  const int n0 = (swz & 7) << 7;
  const int tid = threadIdx.x;
  const int lane = tid & 63;
  const int wv = tid >> 6;
  const int mw = (wv >> 1) << 6;
  const int nw = (wv & 1) << 6;

  __shared__ __align__(16) u16 Alds[128 * 32];
  __shared__ __align__(16) u16 Blds[128 * 32];

  f32x4 acc[4][4] = {};

  for (int kt = 0; kt < 32; ++kt) {
    const int k0 = kt << 5;
#pragma unroll
    for (int i = 0; i < 2; ++i) {
      const int off = (i << 11) + (tid << 3);
      const int row = off >> 5;
      const int col = off & 31;
      async_cp16(&Alds[off], A + (size_t)(m0 + row) * 1024 + k0 + col);
      async_cp16(&Blds[off], B + (size_t)(n0 + row) * 1024 + k0 + col);
    }
    __syncthreads();  // drains vmcnt -> LDS ready
    bf16x8 af[4], bf[4];
#pragma unroll
    for (int mi = 0; mi < 4; ++mi)
      af[mi] = *(const bf16x8*)&Alds[((mw + (mi << 4) + (lane & 15)) << 5) +
                                     ((lane >> 4) << 3)];
#pragma unroll
    for (int ni = 0; ni < 4; ++ni)
      bf[ni] = *(const bf16x8*)&Blds[((nw + (ni << 4) + (lane & 15)) << 5) +
                                     ((lane >> 4) << 3)];
#pragma unroll
    for (int mi = 0; mi < 4; ++mi)
#pragma unroll
      for (int ni = 0; ni < 4; ++ni)
        acc[mi][ni] = __builtin_amdgcn_mfma_f32_16x16x32_bf16(
            af[mi], bf[ni], acc[mi][ni], 0, 0, 0);
    __syncthreads();
  }

  float bv[4];
#pragma unroll
  for (int ni = 0; ni < 4; ++ni)
    bv[ni] = bias[n0 + nw + (ni << 4) + (lane & 15)];
#pragma unroll
  for (int mi = 0; mi < 4; ++mi) {
#pragma unroll
    for (int r = 0; r < 4; ++r) {
      const int row = m0 + mw + (mi << 4) + ((lane >> 4) << 2) + r;
      float* cp = C + (size_t)row * 1024 + n0 + nw + (lane & 15);
#pragma unroll
      for (int ni = 0; ni < 4; ++ni) cp[ni << 4] = acc[mi][ni][r] + bv[ni];
    }
  }
}

// ---------------- Phase 2: recurrent scan (wave-independent) ----------------
// Wave (wg, wv): batches [16g,+16), j in [64*wloc + 16*wv, +16), all k.
// af[kk] = Wh[j0+l16][32kk+8lhi..+8] pinned in AGPRs (128 regs).
// Per step: issue 64 u64 h-pack loads (2 halves), epoch-verify w/ retry,
// 32 MFMAs, tanh, publish 1 u64 pack, fire-and-forget out + xp prefetch.

#define POLL_HALF(QARR, KBASE)                                                \
  {                                                                           \
    unsigned okm = 0;                                                         \
    while (okm != 0xFFFFFFFFu) {                                              \
      _Pragma("unroll") for (int i = 0; i < 16; ++i) {                        \
        if (!(okm & (1u << (2 * i))))                                         \
          QARR[2 * i] =                                                       \
              __hip_atomic_load(Hs + (((KBASE) + i) << 3), __ATOMIC_RELAXED,  \
                                __HIP_MEMORY_SCOPE_AGENT);                    \
        if (!(okm & (2u << (2 * i))))                                         \
          QARR[2 * i + 1] =                                                   \
              __hip_atomic_load(Hs + ((((KBASE) + i) << 3) + 1),              \
                                __ATOMIC_RELAXED, __HIP_MEMORY_SCOPE_AGENT);  \
      }                                                                       \
      _Pragma("unroll") for (int i = 0; i < 32; ++i) {                        \
        if (!(okm & (1u << i))) {                                             \
          const unsigned c = ((unsigned)QARR[i] & 1u) |                       \
                             ((((unsigned)(QARR[i] >> 16)) & 1u) << 1);       \
          if (c == expect) okm |= (1u << i);                                  \
        }                                                                     \
      }                                                                       \
    }                                                                         \
  }

__global__ __launch_bounds__(256, 1) void rnn_scan(float* __restrict__ out,
                                                   const u16* __restrict__ Wh,
                                                   u64* __restrict__ H64) {
  const int wg = blockIdx.x;   // 0..63
  const int g = wg & 3;        // group (16 batches)
  const int wloc = wg >> 2;    // 0..15
  const int b0 = g << 4;
  const int lane = threadIdx.x & 63;
  const int wv = threadIdx.x >> 6;
  const int l16 = lane & 15;
  const int lhi = lane >> 4;
  const int J0w = (wloc << 6) + (wv << 4);  // wave's 16-j base

  // A-frags (full K): af[kk] = Wh[J0w+l16][32kk + 8lhi .. +8]
  bf16x8 af[32];
  {
    const u16* wp = Wh + (size_t)(J0w + l16) * 1024 + (lhi << 3);
#pragma unroll
    for (int kk = 0; kk < 32; ++kk) af[kk] = *(const bf16x8*)(wp + (kk << 5));
  }
#pragma unroll
  for (int kk = 0; kk < 32; ++kk) asm volatile("" : "+a"(af[kk]));  // -> AGPR

  const int b = b0 + l16;
  float* pout = out + ((size_t)b << 19) + J0w + (lhi << 2);  // b*512*1024 + j
  const int hw = (b << 8) + (J0w >> 2) + lhi;  // own h pack (4 consecutive j)
  const int hrb = (b << 8) + (lhi << 1);       // read base; + kk*8 (+1)

  f32x4 xp = __builtin_nontemporal_load((const f32x4*)pout);  // t=0 prefetch

#pragma unroll 1
  for (int t = 0; t < 512; ++t) {
    // keep weights pinned in AGPRs across the loop
#pragma unroll
    for (int kk = 0; kk < 32; ++kk) asm volatile("" : "+a"(af[kk]));

    f32x4 acc = {0.f, 0.f, 0.f, 0.f};
    if (t > 0) {
      const unsigned expect = 1u + ((((unsigned)t - 1u) >> 1) & 1u);
      const u64* Hs = H64 + (((t - 1) & 1) << 14) + hrb;
      u64 q0[32], q1[32];
      // issue both halves' loads up front (one MALL RTT together)
#pragma unroll
      for (int i = 0; i < 16; ++i) {
        q0[2 * i] = __hip_atomic_load(Hs + (i << 3), __ATOMIC_RELAXED,
                                      __HIP_MEMORY_SCOPE_AGENT);
        q0[2 * i + 1] = __hip_atomic_load(Hs + ((i << 3) + 1), __ATOMIC_RELAXED,
                                          __HIP_MEMORY_SCOPE_AGENT);
      }
#pragma unroll
      for (int i = 0; i < 16; ++i) {
        q1[2 * i] = __hip_atomic_load(Hs + (((16 + i) << 3)), __ATOMIC_RELAXED,
                                      __HIP_MEMORY_SCOPE_AGENT);
        q1[2 * i + 1] = __hip_atomic_load(Hs + (((16 + i) << 3) + 1),
                                          __ATOMIC_RELAXED,
                                          __HIP_MEMORY_SCOPE_AGENT);
      }
      // verify half 0, consume (kk = 0..15)
      POLL_HALF(q0, 0)
#pragma unroll
      for (int i = 0; i < 16; ++i) {
        union { u64 qq[2]; bf16x8 v; } u;
        u.qq[0] = q0[2 * i];
        u.qq[1] = q0[2 * i + 1];
        acc = __builtin_amdgcn_mfma_f32_16x16x32_bf16(af[i], u.v, acc, 0, 0, 0);
      }
      // verify half 1, consume (kk = 16..31)
      POLL_HALF(q1, 16)
#pragma unroll
      for (int i = 0; i < 16; ++i) {
        union { u64 qq[2]; bf16x8 v; } u;
        u.qq[0] = q1[2 * i];
        u.qq[1] = q1[2 * i + 1];
        acc = __builtin_amdgcn_mfma_f32_16x16x32_bf16(af[16 + i], u.v, acc, 0,
                                                      0, 0);
      }
    }

    const float h0 = tanhf(xp[0] + acc[0]);
    const float h1 = tanhf(xp[1] + acc[1]);
    const float h2 = tanhf(xp[2] + acc[2]);
    const float h3 = tanhf(xp[3] + acc[3]);

    // publish h with epoch code embedded (single 8B store, no waits)
    const unsigned code = 1u + (((unsigned)t >> 1) & 1u);
    const u64 pack = (u64)f2bf_par(h0, code & 1u) |
                     ((u64)f2bf_par(h1, (code >> 1) & 1u) << 16) |
                     ((u64)f2bf(h2) << 32) | ((u64)f2bf(h3) << 48);
    __hip_atomic_store(H64 + ((t & 1) << 14) + hw, pack, __ATOMIC_RELAXED,
                       __HIP_MEMORY_SCOPE_AGENT);

    // fire-and-forget output + next xp prefetch (issued after publish)
    f32x4 hv;
    hv[0] = h0; hv[1] = h1; hv[2] = h2; hv[3] = h3;
    __builtin_nontemporal_store(hv, (f32x4*)(pout + ((size_t)t << 10)));
    if (t < 511)
      xp = __builtin_nontemporal_load(
          (const f32x4*)(pout + ((size_t)(t + 1) << 10)));
  }
}

// ---------------- launcher ----------------

extern "C" void kernel_launch(void* const* d_in, const int* in_sizes, int n_in,
                              void* d_out, int out_size, void* d_ws,
                              size_t ws_size, hipStream_t stream) {
  const float* x = (const float*)d_in[0];     // [64][512][1024]
  const float* W = (const float*)d_in[1];     // [1024][2048]
  const float* bias = (const float*)d_in[2];  // [1024]
  float* out = (float*)d_out;                 // [64][512][1024]

  char* ws = (char*)d_ws;
  u16* xb = (u16*)ws;                           // 67,108,864 B
  u16* Wxb = (u16*)(ws + 67108864);             //  2,097,152 B
  u16* Whb = (u16*)(ws + 69206016);             //  2,097,152 B
  u64* Hbuf = (u64*)(ws + 71303168);            //    262,144 B (2 x 64 x 1024 bf16)

  (void)hipMemsetAsync(Hbuf, 0, 262144, stream);  // epoch bits -> 0 (stale)
  conv_x_kernel<<<16384, 256, 0, stream>>>(x, xb);
  conv_w_kernel<<<1024, 256, 0, stream>>>(W, Wxb, Whb);
  gemm_xp<<<2048, 256, 0, stream>>>(xb, Wxb, bias, out);
  rnn_scan<<<64, 256, 0, stream>>>(out, Whb, Hbuf);
}

// Round 6
// 2275.311 us; speedup vs baseline: 3.8433x; 3.8433x over previous
//
#include <hip/hip_runtime.h>

// RNN: xp = x@Wx^T + b (GEMM, bf16 MFMA), then 512-step scan
// h_t = tanh(xp_t + h_{t-1}@Wh^T).
// Scan: 4 groups x 16 WGs x 8 waves (512 thr). WG: 16 batches x 64 j.
// Wave wv: k-slice [128wv,+128) -> af[4][4] = 64 VGPRs (fits, no spill).
// Cross-WG exchange: h packs carry 2-bit epoch in bf16 LSBs; consumers poll
// the data itself (relaxed agent-scope loads to MALL). No fences, no flags,
// no producer waits. Cross-wave K-reduce via LDS (1 barrier/step).

typedef unsigned short u16;
typedef unsigned long long u64;
typedef __attribute__((ext_vector_type(4))) float f32x4;
typedef __attribute__((ext_vector_type(8))) short bf16x8;

__device__ __forceinline__ u16 f2bf(float f) {
  unsigned u = __builtin_bit_cast(unsigned, f);
  unsigned r = (u + 0x7fffu + ((u >> 16) & 1u)) >> 16;  // RTN-even
  return (u16)r;
}

// bf16 with bit0 forced to `bit` (<=1 ULP error: trunc or trunc+1)
__device__ __forceinline__ u16 f2bf_par(float f, unsigned bit) {
  unsigned rt = __builtin_bit_cast(unsigned, f) >> 16;  // truncate
  return (u16)(((rt & 1u) == bit) ? rt : rt + 1u);
}

// tanh via single exp: 1 - 2/(e^{2x}+1); exact at +/-inf, monotone, ~2ulp
__device__ __forceinline__ float fast_tanh(float x) {
  float e = __expf(2.0f * x);
  return 1.0f - 2.0f / (e + 1.0f);
}

__device__ __forceinline__ void async_cp16(u16* lds, const u16* g) {
  __builtin_amdgcn_global_load_lds(
      (const __attribute__((address_space(1))) unsigned int*)g,
      (__attribute__((address_space(3))) unsigned int*)lds, 16, 0, 0);
}

// ---------------- conversion kernels ----------------

__global__ __launch_bounds__(256) void conv_x_kernel(const float* __restrict__ in,
                                                     u16* __restrict__ outb) {
  const size_t i = (size_t)blockIdx.x * 256 + threadIdx.x;  // 8-elem chunk id
  const float4* p = (const float4*)(in + (i << 3));
  float4 a = p[0], b = p[1];
  bf16x8 v;
  v[0] = (short)f2bf(a.x); v[1] = (short)f2bf(a.y);
  v[2] = (short)f2bf(a.z); v[3] = (short)f2bf(a.w);
  v[4] = (short)f2bf(b.x); v[5] = (short)f2bf(b.y);
  v[6] = (short)f2bf(b.z); v[7] = (short)f2bf(b.w);
  *(bf16x8*)(outb + (i << 3)) = v;
}

__global__ __launch_bounds__(256) void conv_w_kernel(const float* __restrict__ W,
                                                     u16* __restrict__ Wx,
                                                     u16* __restrict__ Wh) {
  const int i = blockIdx.x * 256 + threadIdx.x;  // 8-elem chunk id, 2048/row
  const int j = i >> 8;          // row 0..1023
  const int c = (i & 255) << 3;  // col 0..2040
  const float4* p = (const float4*)(W + (size_t)j * 2048 + c);
  float4 a = p[0], b = p[1];
  bf16x8 v;
  v[0] = (short)f2bf(a.x); v[1] = (short)f2bf(a.y);
  v[2] = (short)f2bf(a.z); v[3] = (short)f2bf(a.w);
  v[4] = (short)f2bf(b.x); v[5] = (short)f2bf(b.y);
  v[6] = (short)f2bf(b.z); v[7] = (short)f2bf(b.w);
  u16* dst = (c < 1024) ? (Wx + (size_t)j * 1024 + c)
                        : (Wh + (size_t)j * 1024 + (c - 1024));
  *(bf16x8*)dst = v;
}

// ---------------- Phase 1: xp GEMM (m97 structure) ----------------

__global__ __launch_bounds__(256, 2) void gemm_xp(const u16* __restrict__ A,
                                                  const u16* __restrict__ B,
                                                  const float* __restrict__ bias,
                                                  float* __restrict__ C) {
  const int bid = blockIdx.x;                    // 2048 blocks
  const int swz = (bid & 7) * 256 + (bid >> 3);  // XCD-aware swizzle (nwg%8==0)
  const int m0 = (swz >> 3) << 7;
  const int n0 = (swz & 7) << 7;
  const int tid = threadIdx.x;
  const int lane = tid & 63;
  const int wv = tid >> 6;
  const int mw = (wv >> 1) << 6;
  const int nw = (wv & 1) << 6;

  __shared__ __align__(16) u16 Alds[128 * 32];
  __shared__ __align__(16) u16 Blds[128 * 32];

  f32x4 acc[4][4] = {};

  for (int kt = 0; kt < 32; ++kt) {
    const int k0 = kt << 5;
#pragma unroll
    for (int i = 0; i < 2; ++i) {
      const int off = (i << 11) + (tid << 3);
      const int row = off >> 5;
      const int col = off & 31;
      async_cp16(&Alds[off], A + (size_t)(m0 + row) * 1024 + k0 + col);
      async_cp16(&Blds[off], B + (size_t)(n0 + row) * 1024 + k0 + col);
    }
    __syncthreads();  // drains vmcnt -> LDS ready
    bf16x8 af[4], bf[4];
#pragma unroll
    for (int mi = 0; mi < 4; ++mi)
      af[mi] = *(const bf16x8*)&Alds[((mw + (mi << 4) + (lane & 15)) << 5) +
                                     ((lane >> 4) << 3)];
#pragma unroll
    for (int ni = 0; ni < 4; ++ni)
      bf[ni] = *(const bf16x8*)&Blds[((nw + (ni << 4) + (lane & 15)) << 5) +
                                     ((lane >> 4) << 3)];
#pragma unroll
    for (int mi = 0; mi < 4; ++mi)
#pragma unroll
      for (int ni = 0; ni < 4; ++ni)
        acc[mi][ni] = __builtin_amdgcn_mfma_f32_16x16x32_bf16(
            af[mi], bf[ni], acc[mi][ni], 0, 0, 0);
    __syncthreads();
  }

  float bv[4];
#pragma unroll
  for (int ni = 0; ni < 4; ++ni)
    bv[ni] = bias[n0 + nw + (ni << 4) + (lane & 15)];
#pragma unroll
  for (int mi = 0; mi < 4; ++mi) {
#pragma unroll
    for (int r = 0; r < 4; ++r) {
      const int row = m0 + mw + (mi << 4) + ((lane >> 4) << 2) + r;
      float* cp = C + (size_t)row * 1024 + n0 + nw + (lane & 15);
#pragma unroll
      for (int ni = 0; ni < 4; ++ni) cp[ni << 4] = acc[mi][ni][r] + bv[ni];
    }
  }
}

// ---------------- Phase 2: recurrent scan ----------------
// WG (g=wg&3, wloc=wg>>2): batches [16g,+16), j [64wloc,+64). 8 waves.
// Wave wv: k [128wv,+128). af[jt][kk] = Wh[64wloc+16jt+l16][128wv+32kk+8lhi..+8]
// B-frag: h[b=16g+l16][same k] = 2 u64 epoch-coded packs per kk.
// Step: poll 8 packs (wave-uniform retry) -> 16 MFMA -> LDS write -> barrier
// -> waves 0-3 reduce 8 partials for jt=wv, tanh, publish pack, out store.

__global__ __launch_bounds__(512, 1) void rnn_scan(float* __restrict__ out,
                                                   const u16* __restrict__ Wh,
                                                   u64* __restrict__ H64) {
  const int wg = blockIdx.x;   // 0..63
  const int g = wg & 3;        // group (16 batches)
  const int wloc = wg >> 2;    // 0..15 (64-j slice)
  const int tid = threadIdx.x;
  const int lane = tid & 63;
  const int wv = tid >> 6;     // 0..7 (k-slice; <4 also j-tile owner)
  const int l16 = lane & 15;
  const int lhi = lane >> 4;

  __shared__ __align__(16) f32x4 red[2][8][4][64];  // 64KB, dbuf

  // A-frags: af[jt][kk] = Wh[64wloc+16jt+l16][128wv + 32kk + 8lhi .. +8]
  bf16x8 af[4][4];
  {
    const u16* wp =
        Wh + (size_t)((wloc << 6) + l16) * 1024 + (wv << 7) + (lhi << 3);
#pragma unroll
    for (int jt = 0; jt < 4; ++jt)
#pragma unroll
      for (int kk = 0; kk < 4; ++kk)
        af[jt][kk] = *(const bf16x8*)(wp + (jt << 14) + (kk << 5));
  }

  const int b = (g << 4) + l16;
  // consumer: pack base = (b<<8) + 32wv + 2lhi; frag kk at +8kk, +8kk+1
  const int hrb = (b << 8) + (wv << 5) + (lhi << 1);
  // producer (waves 0-3): 4 consecutive j = 64wloc + 16wv + 4lhi
  const int wvp = wv & 3;
  const int j0 = (wloc << 6) + (wvp << 4) + (lhi << 2);
  const int hw = (b << 8) + (j0 >> 2);
  float* pout = out + ((size_t)b << 19) + j0;  // b*512*1024 + j

  f32x4 xp;
  if (wv < 4) xp = __builtin_nontemporal_load((const f32x4*)pout);

#pragma unroll 1
  for (int t = 0; t < 512; ++t) {
    f32x4 acc[4] = {};
    if (t > 0) {
      const unsigned expect = 1u + ((((unsigned)t - 1u) >> 1) & 1u);
      const u64* Hs = H64 + (((t - 1) & 1) << 14) + hrb;
      u64 q[8];
      while (true) {
#pragma unroll
        for (int i = 0; i < 4; ++i) {
          q[2 * i] = __hip_atomic_load(Hs + (i << 3), __ATOMIC_RELAXED,
                                       __HIP_MEMORY_SCOPE_AGENT);
          q[2 * i + 1] = __hip_atomic_load(Hs + (i << 3) + 1, __ATOMIC_RELAXED,
                                           __HIP_MEMORY_SCOPE_AGENT);
        }
        unsigned ok = 1u;
#pragma unroll
        for (int i = 0; i < 8; ++i) {
          const unsigned c = ((unsigned)q[i] & 1u) |
                             ((((unsigned)(q[i] >> 16)) & 1u) << 1);
          ok &= (unsigned)(c == expect);
        }
        if (__all((int)ok)) break;
      }
#pragma unroll
      for (int kk = 0; kk < 4; ++kk) {
        union { u64 qq[2]; bf16x8 v; } u;
        u.qq[0] = q[2 * kk];
        u.qq[1] = q[2 * kk + 1];
#pragma unroll
        for (int jt = 0; jt < 4; ++jt)
          acc[jt] = __builtin_amdgcn_mfma_f32_16x16x32_bf16(af[jt][kk], u.v,
                                                            acc[jt], 0, 0, 0);
      }
    }

    const int rb = t & 1;
#pragma unroll
    for (int jt = 0; jt < 4; ++jt) red[rb][wv][jt][lane] = acc[jt];
    __syncthreads();

    if (wv < 4) {
      f32x4 s = red[rb][0][wvp][lane];
#pragma unroll
      for (int w = 1; w < 8; ++w) s += red[rb][w][wvp][lane];

      const float h0 = fast_tanh(xp[0] + s[0]);
      const float h1 = fast_tanh(xp[1] + s[1]);
      const float h2 = fast_tanh(xp[2] + s[2]);
      const float h3 = fast_tanh(xp[3] + s[3]);

      // publish h with epoch code embedded (single 8B store, no waits)
      const unsigned code = 1u + (((unsigned)t >> 1) & 1u);
      const u64 pack = (u64)f2bf_par(h0, code & 1u) |
                       ((u64)f2bf_par(h1, (code >> 1) & 1u) << 16) |
                       ((u64)f2bf(h2) << 32) | ((u64)f2bf(h3) << 48);
      __hip_atomic_store(H64 + ((t & 1) << 14) + hw, pack, __ATOMIC_RELAXED,
                         __HIP_MEMORY_SCOPE_AGENT);

      // fire-and-forget output + next xp prefetch (issued after publish)
      f32x4 hv;
      hv[0] = h0; hv[1] = h1; hv[2] = h2; hv[3] = h3;
      __builtin_nontemporal_store(hv, (f32x4*)(pout + ((size_t)t << 10)));
      if (t < 511)
        xp = __builtin_nontemporal_load(
            (const f32x4*)(pout + ((size_t)(t + 1) << 10)));
    }
  }
}

// ---------------- launcher ----------------

extern "C" void kernel_launch(void* const* d_in, const int* in_sizes, int n_in,
                              void* d_out, int out_size, void* d_ws,
                              size_t ws_size, hipStream_t stream) {
  const float* x = (const float*)d_in[0];     // [64][512][1024]
  const float* W = (const float*)d_in[1];     // [1024][2048]
  const float* bias = (const float*)d_in[2];  // [1024]
  float* out = (float*)d_out;                 // [64][512][1024]

  char* ws = (char*)d_ws;
  u16* xb = (u16*)ws;                           // 67,108,864 B
  u16* Wxb = (u16*)(ws + 67108864);             //  2,097,152 B
  u16* Whb = (u16*)(ws + 69206016);             //  2,097,152 B
  u64* Hbuf = (u64*)(ws + 71303168);            //    262,144 B (2 x 64 x 1024 bf16)

  (void)hipMemsetAsync(Hbuf, 0, 262144, stream);  // epoch bits -> 0 (stale)
  conv_x_kernel<<<16384, 256, 0, stream>>>(x, xb);
  conv_w_kernel<<<1024, 256, 0, stream>>>(W, Wxb, Whb);
  gemm_xp<<<2048, 256, 0, stream>>>(xb, Wxb, bias, out);
  rnn_scan<<<64, 512, 0, stream>>>(out, Whb, Hbuf);
}